// Round 1
// baseline (270.030 us; speedup 1.0000x reference)
//
#include <hip/hip_runtime.h>
#include <cstddef>

#define EPS1f 1e-6f
#define WDf   1e-5f

constexpr int Bsz = 512, Fsz = 512, Csz = 500, Zsz = 64, Ssz = 100;
constexpr int CCH = 125, NCH = 4;   // C-chunks for the hot kernel

// ---------------- helpers ----------------
__device__ inline float block_reduce_sum(float v, float* red) {
  #pragma unroll
  for (int off = 32; off > 0; off >>= 1) v += __shfl_down(v, off, 64);
  const int lane = threadIdx.x & 63, wid = threadIdx.x >> 6;
  if (lane == 0) red[wid] = v;
  __syncthreads();
  float r = 0.f;
  if (threadIdx.x == 0) {
    const int nw = blockDim.x >> 6;
    for (int i = 0; i < nw; ++i) r += red[i];
  }
  __syncthreads();
  return r;   // valid in thread 0 only
}

// ---------------- generic 64x64 tile GEMM: out = act(A@W + bias) ----------------
template <bool RELU>
__global__ __launch_bounds__(256) void gemm_bias(
    const float* __restrict__ A, const float* __restrict__ W,
    const float* __restrict__ bias, float* __restrict__ out,
    int M, int N, int K) {
  __shared__ float As[16][68];   // [k][m], padded
  __shared__ float Ws[16][64];   // [k][n]
  const int bn = blockIdx.x * 64, bm = blockIdx.y * 64;
  const int tid = threadIdx.x;
  const int tn = tid & 15, tm = tid >> 4;
  const int arow = tid >> 2, ak = (tid & 3) * 4;
  const int wk = tid >> 4, wn = (tid & 15) * 4;
  float acc[4][4] = {};
  for (int kt = 0; kt < K; kt += 16) {
    float4 av = *reinterpret_cast<const float4*>(A + (size_t)(bm + arow) * K + kt + ak);
    float4 wv;
    const int nb = bn + wn;
    const float* wrow = W + (size_t)(kt + wk) * N;
    if (nb + 3 < N) {
      wv = *reinterpret_cast<const float4*>(wrow + nb);
    } else {
      wv.x = (nb + 0 < N) ? wrow[nb + 0] : 0.f;
      wv.y = (nb + 1 < N) ? wrow[nb + 1] : 0.f;
      wv.z = (nb + 2 < N) ? wrow[nb + 2] : 0.f;
      wv.w = (nb + 3 < N) ? wrow[nb + 3] : 0.f;
    }
    __syncthreads();
    As[ak + 0][arow] = av.x; As[ak + 1][arow] = av.y;
    As[ak + 2][arow] = av.z; As[ak + 3][arow] = av.w;
    *reinterpret_cast<float4*>(&Ws[wk][wn]) = wv;
    __syncthreads();
    #pragma unroll
    for (int k = 0; k < 16; ++k) {
      float4 a4 = *reinterpret_cast<const float4*>(&As[k][tm * 4]);
      float4 w4 = *reinterpret_cast<const float4*>(&Ws[k][tn * 4]);
      float ar[4] = {a4.x, a4.y, a4.z, a4.w};
      float wr[4] = {w4.x, w4.y, w4.z, w4.w};
      #pragma unroll
      for (int i = 0; i < 4; ++i) {
        #pragma unroll
        for (int j = 0; j < 4; ++j) acc[i][j] = fmaf(ar[i], wr[j], acc[i][j]);
      }
    }
  }
  #pragma unroll
  for (int j = 0; j < 4; ++j) {
    const int n = bn + tn * 4 + j;
    if (n >= N) continue;
    const float bv = bias[n];
    #pragma unroll
    for (int i = 0; i < 4; ++i) {
      const int m = bm + tm * 4 + i;
      float v = acc[i][j] + bv;
      if (RELU) v = fmaxf(v, 0.f);
      out[(size_t)m * N + n] = v;
    }
  }
}

// ---------------- cov_diag sqrt ----------------
__global__ __launch_bounds__(256) void cov_kernel(const float* __restrict__ R,
                                                  float* __restrict__ sqrtcov) {
  const int c = blockIdx.x * 256 + threadIdx.x;
  if (c >= Csz) return;
  const float* r = R + (size_t)c * Zsz;
  float s = 1.f;
  #pragma unroll
  for (int z = 0; z < Zsz; ++z) s = fmaf(r[z], r[z], s);
  sqrtcov[c] = sqrtf(s);
}

// ---------------- mu epilogue: indiv_prob, CE row-sums, transposed r_mu / Y ----------------
__global__ __launch_bounds__(256) void mu_post(
    const float* __restrict__ nm, const float* __restrict__ Y,
    const float* __restrict__ sqrtcov, float* __restrict__ out_prob,
    float* __restrict__ rmuT, float* __restrict__ yT, float* __restrict__ ce_b) {
  __shared__ float red[4];
  const int b = blockIdx.x;
  float ce = 0.f;
  for (int c = threadIdx.x; c < Csz; c += 256) {
    const float v = nm[(size_t)b * Csz + c];
    const float y = Y[(size_t)b * Csz + c];
    const float z = v * 1.70169f;
    const float sp = 1.f / (1.f + __expf(-z));
    const float p = fmaf(sp, 1.f - EPS1f, 0.5f * EPS1f);
    const float q = fmaf(1.f - sp, 1.f - EPS1f, 0.5f * EPS1f);
    out_prob[(size_t)b * Csz + c] = p;
    ce += __logf((y > 0.5f) ? p : q);
    rmuT[(size_t)c * Bsz + b] = v * sqrtcov[c];
    yT[(size_t)c * Bsz + b] = y;
  }
  const float tot = block_reduce_sum(ce, red);
  if (threadIdx.x == 0) ce_b[b] = tot;
}

// ---------------- HOT: fused einsum + probit + log-likelihood partial C-reduction ----------------
__global__ __launch_bounds__(256) void logprob_kernel(
    const float* __restrict__ noise, const float* __restrict__ R,
    const float* __restrict__ rmuT, const float* __restrict__ yT,
    float* __restrict__ lp_part) {
  const int blk = blockIdx.x;          // grid = NCH * 2 * Ssz = 800
  const int s = blk % Ssz;
  const int t2 = blk / Ssz;
  const int half = t2 & 1;
  const int ch = t2 >> 1;
  const int b = half * 256 + threadIdx.x;

  float nz[Zsz];
  const float4* np4 = reinterpret_cast<const float4*>(noise + ((size_t)s * Bsz + b) * Zsz);
  #pragma unroll
  for (int q = 0; q < Zsz / 4; ++q) {
    float4 v = np4[q];
    nz[4 * q + 0] = v.x; nz[4 * q + 1] = v.y;
    nz[4 * q + 2] = v.z; nz[4 * q + 3] = v.w;
  }

  const float* Rb = R + (size_t)ch * CCH * Zsz;     // uniform across lanes
  const float* rmuc = rmuT + (size_t)ch * CCH * Bsz + b;
  const float* yc = yT + (size_t)ch * CCH * Bsz + b;

  float acc = 0.f;
  for (int ci = 0; ci < CCH; ++ci) {
    const float* rr = Rb + ci * Zsz;
    float d0 = 0.f, d1 = 0.f, d2 = 0.f, d3 = 0.f;
    #pragma unroll
    for (int z = 0; z < Zsz; z += 4) {
      d0 = fmaf(nz[z + 0], rr[z + 0], d0);
      d1 = fmaf(nz[z + 1], rr[z + 1], d1);
      d2 = fmaf(nz[z + 2], rr[z + 2], d2);
      d3 = fmaf(nz[z + 3], rr[z + 3], d3);
    }
    const float x = (d0 + d1) + (d2 + d3) + rmuc[(size_t)ci * Bsz];
    const float y = yc[(size_t)ci * Bsz];
    const float t = (y > 0.5f) ? x : -x;
    // log( Phi(t)*(1-eps) + eps/2 ): exact for both Y branches, no 1-E cancellation
    const float Phi = 0.5f * erfcf(t * -0.70710678118654752f);
    const float E = fmaf(Phi, 1.f - EPS1f, 0.5f * EPS1f);
    acc += __logf(E);
  }
  lp_part[((size_t)(ch * Ssz + s)) * Bsz + b] = acc;
}

// ---------------- per-b log-sum-exp over S ----------------
__global__ __launch_bounds__(256) void nll_kernel(const float* __restrict__ lp_part,
                                                  float* __restrict__ nll_b) {
  const int b = blockIdx.x * 256 + threadIdx.x;
  if (b >= Bsz) return;
  float m = -1e30f;
  for (int s = 0; s < Ssz; ++s) {
    float lp = lp_part[(size_t)(0 * Ssz + s) * Bsz + b]
             + lp_part[(size_t)(1 * Ssz + s) * Bsz + b]
             + lp_part[(size_t)(2 * Ssz + s) * Bsz + b]
             + lp_part[(size_t)(3 * Ssz + s) * Bsz + b];
    m = fmaxf(m, lp);
  }
  float se = 0.f;
  for (int s = 0; s < Ssz; ++s) {
    float lp = lp_part[(size_t)(0 * Ssz + s) * Bsz + b]
             + lp_part[(size_t)(1 * Ssz + s) * Bsz + b]
             + lp_part[(size_t)(2 * Ssz + s) * Bsz + b]
             + lp_part[(size_t)(3 * Ssz + s) * Bsz + b];
    se += __expf(lp - m);
  }
  const float Eprob = se * (1.f / (float)Ssz);
  nll_b[b] = -__logf(Eprob) - m;
}

// ---------------- L2 partials ----------------
__global__ __launch_bounds__(256) void l2_partial(
    const float* __restrict__ Wa, int na, const float* __restrict__ Wb, int nb,
    const float* __restrict__ Wc, int nc, const float* __restrict__ Wd, int nd,
    float* __restrict__ part) {
  __shared__ float red[4];
  const int gid = blockIdx.x * 256 + threadIdx.x;
  const int stride = gridDim.x * 256;
  float s = 0.f;
  for (int i = gid; i < na; i += stride) { float v = Wa[i]; s = fmaf(v, v, s); }
  for (int i = gid; i < nb; i += stride) { float v = Wb[i]; s = fmaf(v, v, s); }
  for (int i = gid; i < nc; i += stride) { float v = Wc[i]; s = fmaf(v, v, s); }
  for (int i = gid; i < nd; i += stride) { float v = Wd[i]; s = fmaf(v, v, s); }
  const float tot = block_reduce_sum(s, red);
  if (threadIdx.x == 0) part[blockIdx.x] = tot;
}

// ---------------- final scalars ----------------
__global__ __launch_bounds__(256) void finals_kernel(
    const float* __restrict__ nll_b, const float* __restrict__ ce_b,
    const float* __restrict__ l2_part, int nparts, float* __restrict__ out4) {
  __shared__ float red[4];
  const int t = threadIdx.x;
  const float snll = block_reduce_sum(nll_b[t] + nll_b[t + 256], red);
  const float sce = block_reduce_sum(ce_b[t] + ce_b[t + 256], red);
  const float sl2 = block_reduce_sum((t < nparts) ? l2_part[t] : 0.f, red);
  if (t == 0) {
    const float nll = snll / (float)Bsz;
    const float marg = -sce / (float)Bsz;
    const float l2v = WDf * sl2;
    out4[0] = nll;
    out4[1] = marg;
    out4[2] = l2v;
    out4[3] = l2v + nll;
  }
}

// ---------------- launch ----------------
extern "C" void kernel_launch(void* const* d_in, const int* in_sizes, int n_in,
                              void* d_out, int out_size, void* d_ws, size_t ws_size,
                              hipStream_t stream) {
  const float* X = (const float*)d_in[0];
  const float* Y = (const float*)d_in[1];
  const float* noise = (const float*)d_in[2];
  const float* W1 = (const float*)d_in[3];
  const float* b1 = (const float*)d_in[4];
  const float* W2 = (const float*)d_in[5];
  const float* b2 = (const float*)d_in[6];
  const float* W3 = (const float*)d_in[7];
  const float* b3 = (const float*)d_in[8];
  const float* Wmu = (const float*)d_in[9];
  const float* bmu = (const float*)d_in[10];
  const float* rss = (const float*)d_in[11];

  float* ws = (float*)d_ws;
  float* h1 = ws;                       // 512*128   = 65536
  float* h2 = h1 + 65536;               // 512*256   = 131072
  float* feat = h2 + 131072;            // 512*256   = 131072
  float* nm = feat + 131072;            // 512*500   = 256000
  float* sqrtcov = nm + 256000;         // 512 (padded)
  float* rmuT = sqrtcov + 512;          // 500*512   = 256000
  float* yT = rmuT + 256000;            // 500*512   = 256000
  float* lp_part = yT + 256000;         // 4*100*512 = 204800
  float* ce_b = lp_part + 204800;       // 512
  float* nll_b = ce_b + 512;            // 512
  float* l2_part = nll_b + 512;         // 64

  float* out_prob = (float*)d_out;
  float* out4 = out_prob + (size_t)Bsz * Csz;

  // trunk
  gemm_bias<true><<<dim3(2, 8), 256, 0, stream>>>(X, W1, b1, h1, 512, 128, 512);
  gemm_bias<true><<<dim3(4, 8), 256, 0, stream>>>(h1, W2, b2, h2, 512, 256, 128);
  gemm_bias<true><<<dim3(4, 8), 256, 0, stream>>>(h2, W3, b3, feat, 512, 256, 256);
  gemm_bias<false><<<dim3(8, 8), 256, 0, stream>>>(feat, Wmu, bmu, nm, 512, 500, 256);

  cov_kernel<<<dim3(2), 256, 0, stream>>>(rss, sqrtcov);
  mu_post<<<dim3(512), 256, 0, stream>>>(nm, Y, sqrtcov, out_prob, rmuT, yT, ce_b);

  logprob_kernel<<<dim3(NCH * 2 * Ssz), 256, 0, stream>>>(noise, rss, rmuT, yT, lp_part);

  nll_kernel<<<dim3(2), 256, 0, stream>>>(lp_part, nll_b);
  l2_partial<<<dim3(64), 256, 0, stream>>>(W1, 65536, W2, 32768, W3, 65536, Wmu, 128000, l2_part);
  finals_kernel<<<dim3(1), 256, 0, stream>>>(nll_b, ce_b, l2_part, 64, out4);
}

// Round 2
// 240.611 us; speedup vs baseline: 1.1223x; 1.1223x over previous
//
#include <hip/hip_runtime.h>
#include <cstddef>

#define EPS1f 1e-6f
#define WDf   1e-5f

constexpr int Bsz = 512, Fsz = 512, Csz = 500, Zsz = 64, Ssz = 100;
constexpr int CCH = 50, NCH = 10;   // C-chunks for the hot kernel

// ---------------- helpers ----------------
__device__ inline float block_reduce_sum(float v, float* red) {
  #pragma unroll
  for (int off = 32; off > 0; off >>= 1) v += __shfl_down(v, off, 64);
  const int lane = threadIdx.x & 63, wid = threadIdx.x >> 6;
  if (lane == 0) red[wid] = v;
  __syncthreads();
  float r = 0.f;
  if (threadIdx.x == 0) {
    const int nw = blockDim.x >> 6;
    for (int i = 0; i < nw; ++i) r += red[i];
  }
  __syncthreads();
  return r;   // valid in thread 0 only
}

// ---------------- generic 64x64 tile GEMM: out = act(A@W + bias) ----------------
// MU variant additionally writes rmuT[n][m] = (acc+bias)*sqrtcov[n] (float4 along m)
template <bool RELU, bool MU>
__global__ __launch_bounds__(256) void gemm_bias(
    const float* __restrict__ A, const float* __restrict__ W,
    const float* __restrict__ bias, float* __restrict__ out,
    int M, int N, int K,
    float* __restrict__ rmuT, const float* __restrict__ sqrtcov) {
  __shared__ float As[16][68];   // [k][m], padded
  __shared__ float Ws[16][64];   // [k][n]
  const int bn = blockIdx.x * 64, bm = blockIdx.y * 64;
  const int tid = threadIdx.x;
  const int tn = tid & 15, tm = tid >> 4;
  const int arow = tid >> 2, ak = (tid & 3) * 4;
  const int wk = tid >> 4, wn = (tid & 15) * 4;
  float acc[4][4] = {};
  for (int kt = 0; kt < K; kt += 16) {
    float4 av = *reinterpret_cast<const float4*>(A + (size_t)(bm + arow) * K + kt + ak);
    float4 wv;
    const int nb = bn + wn;
    const float* wrow = W + (size_t)(kt + wk) * N;
    if (nb + 3 < N) {
      wv = *reinterpret_cast<const float4*>(wrow + nb);
    } else {
      wv.x = (nb + 0 < N) ? wrow[nb + 0] : 0.f;
      wv.y = (nb + 1 < N) ? wrow[nb + 1] : 0.f;
      wv.z = (nb + 2 < N) ? wrow[nb + 2] : 0.f;
      wv.w = (nb + 3 < N) ? wrow[nb + 3] : 0.f;
    }
    __syncthreads();
    As[ak + 0][arow] = av.x; As[ak + 1][arow] = av.y;
    As[ak + 2][arow] = av.z; As[ak + 3][arow] = av.w;
    *reinterpret_cast<float4*>(&Ws[wk][wn]) = wv;
    __syncthreads();
    #pragma unroll
    for (int k = 0; k < 16; ++k) {
      float4 a4 = *reinterpret_cast<const float4*>(&As[k][tm * 4]);
      float4 w4 = *reinterpret_cast<const float4*>(&Ws[k][tn * 4]);
      float ar[4] = {a4.x, a4.y, a4.z, a4.w};
      float wr[4] = {w4.x, w4.y, w4.z, w4.w};
      #pragma unroll
      for (int i = 0; i < 4; ++i) {
        #pragma unroll
        for (int j = 0; j < 4; ++j) acc[i][j] = fmaf(ar[i], wr[j], acc[i][j]);
      }
    }
  }
  #pragma unroll
  for (int j = 0; j < 4; ++j) {
    const int n = bn + tn * 4 + j;
    if (n >= N) continue;
    const float bv = bias[n];
    if (MU) {
      const float sc = sqrtcov[n];
      float vals[4];
      #pragma unroll
      for (int i = 0; i < 4; ++i) {
        const int m = bm + tm * 4 + i;
        const float v = acc[i][j] + bv;
        out[(size_t)m * N + n] = v;
        vals[i] = v * sc;
      }
      *reinterpret_cast<float4*>(rmuT + (size_t)n * Bsz + bm + tm * 4) =
          make_float4(vals[0], vals[1], vals[2], vals[3]);
    } else {
      #pragma unroll
      for (int i = 0; i < 4; ++i) {
        const int m = bm + tm * 4 + i;
        float v = acc[i][j] + bv;
        if (RELU) v = fmaxf(v, 0.f);
        out[(size_t)m * N + n] = v;
      }
    }
  }
}

// ---------------- cov_diag sqrt ----------------
__global__ __launch_bounds__(256) void cov_kernel(const float* __restrict__ R,
                                                  float* __restrict__ sqrtcov) {
  const int c = blockIdx.x * 256 + threadIdx.x;
  if (c >= Csz) return;
  const float* r = R + (size_t)c * Zsz;
  float s = 1.f;
  #pragma unroll
  for (int z = 0; z < Zsz; ++z) s = fmaf(r[z], r[z], s);
  sqrtcov[c] = sqrtf(s);
}

// ---------------- tiled transpose: in[rows][cols] -> out[cols][rows] ----------------
__global__ __launch_bounds__(256) void transpose_kernel(
    const float* __restrict__ in, float* __restrict__ out, int rows, int cols) {
  __shared__ float tile[64][65];
  const int c0 = blockIdx.x * 64;
  const int r0 = blockIdx.y * 64;
  const int tc = threadIdx.x & 63;
  const int tr4 = threadIdx.x >> 6;
  #pragma unroll
  for (int rr = tr4; rr < 64; rr += 4) {
    const int r = r0 + rr, c = c0 + tc;
    tile[rr][tc] = (c < cols && r < rows) ? in[(size_t)r * cols + c] : 0.f;
  }
  __syncthreads();
  #pragma unroll
  for (int cc = tr4; cc < 64; cc += 4) {
    const int c = c0 + cc, r = r0 + tc;
    if (c < cols && r < rows) out[(size_t)c * rows + r] = tile[tc][cc];
  }
}

// ---------------- mu epilogue: indiv_prob + CE row-sums (all coalesced) ----------------
__global__ __launch_bounds__(256) void mu_post(
    const float* __restrict__ nm, const float* __restrict__ Y,
    float* __restrict__ out_prob, float* __restrict__ ce_b) {
  __shared__ float red[4];
  const int b = blockIdx.x;
  float ce = 0.f;
  for (int c = threadIdx.x; c < Csz; c += 256) {
    const float v = nm[(size_t)b * Csz + c];
    const float y = Y[(size_t)b * Csz + c];
    const float z = v * 1.70169f;
    const float sp = 1.f / (1.f + __expf(-z));
    const float p = fmaf(sp, 1.f - EPS1f, 0.5f * EPS1f);
    const float q = fmaf(1.f - sp, 1.f - EPS1f, 0.5f * EPS1f);
    out_prob[(size_t)b * Csz + c] = p;
    ce += __logf((y > 0.5f) ? p : q);
  }
  const float tot = block_reduce_sum(ce, red);
  if (threadIdx.x == 0) ce_b[b] = tot;
}

// ---------------- HOT: fused einsum + probit + log-likelihood partial C-reduction ----------------
__global__ __launch_bounds__(256, 4) void logprob_kernel(
    const float* __restrict__ noise, const float* __restrict__ R,
    const float* __restrict__ rmuT, const float* __restrict__ yT,
    float* __restrict__ lp_part) {
  const int blk = blockIdx.x;          // grid = NCH * 2 * Ssz = 2000
  const int s = blk % Ssz;
  const int t2 = blk / Ssz;
  const int half = t2 & 1;
  const int ch = t2 >> 1;
  const int b = half * 256 + threadIdx.x;

  // noise row: 16 float4 = 64 VGPRs, resident for the whole kernel
  float4 nz[16];
  const float4* np4 = reinterpret_cast<const float4*>(noise + ((size_t)s * Bsz + b) * Zsz);
  #pragma unroll
  for (int q = 0; q < 16; ++q) nz[q] = np4[q];

  const float* Rb = R + (size_t)ch * CCH * Zsz;     // uniform across lanes -> SGPR
  const float* rmuc = rmuT + (size_t)ch * CCH * Bsz + b;
  const float* yc = yT + (size_t)ch * CCH * Bsz + b;

  float acc = 0.f;
  for (int ci = 0; ci < CCH; ++ci) {
    const float* rr = Rb + ci * Zsz;
    float d0 = 0.f, d1 = 0.f, d2 = 0.f, d3 = 0.f;
    #pragma unroll
    for (int q = 0; q < 16; ++q) {
      d0 = fmaf(nz[q].x, rr[4 * q + 0], d0);
      d1 = fmaf(nz[q].y, rr[4 * q + 1], d1);
      d2 = fmaf(nz[q].z, rr[4 * q + 2], d2);
      d3 = fmaf(nz[q].w, rr[4 * q + 3], d3);
    }
    const float x = (d0 + d1) + (d2 + d3) + rmuc[(size_t)ci * Bsz];
    const float y = yc[(size_t)ci * Bsz];
    const float sgn = fmaf(2.f, y, -1.f);            // exactly +/-1
    const float t = x * sgn;
    // log( Phi(t)*(1-eps) + eps/2 ): exact for both Y branches, no 1-E cancellation
    const float Phi = 0.5f * erfcf(t * -0.70710678118654752f);
    const float E = fmaf(Phi, 1.f - EPS1f, 0.5f * EPS1f);
    acc += __logf(E);
  }
  lp_part[((size_t)(ch * Ssz + s)) * Bsz + b] = acc;
}

// ---------------- sum chunk partials: lp_sum[s*B+b] = sum_ch lp_part ----------------
__global__ __launch_bounds__(256) void lp_reduce(const float* __restrict__ lp_part,
                                                 float* __restrict__ lp_sum) {
  const int i = blockIdx.x * 256 + threadIdx.x;     // over Ssz*Bsz
  float v = 0.f;
  #pragma unroll
  for (int ch = 0; ch < NCH; ++ch) v += lp_part[(size_t)ch * Ssz * Bsz + i];
  lp_sum[i] = v;
}

// ---------------- per-b log-sum-exp over S ----------------
__global__ __launch_bounds__(256) void nll_kernel(const float* __restrict__ lp_sum,
                                                  float* __restrict__ nll_b) {
  const int b = blockIdx.x * 256 + threadIdx.x;
  if (b >= Bsz) return;
  float m = -1e30f;
  for (int s = 0; s < Ssz; ++s) m = fmaxf(m, lp_sum[(size_t)s * Bsz + b]);
  float se = 0.f;
  for (int s = 0; s < Ssz; ++s) se += __expf(lp_sum[(size_t)s * Bsz + b] - m);
  nll_b[b] = -__logf(se * (1.f / (float)Ssz)) - m;
}

// ---------------- L2 partials ----------------
__global__ __launch_bounds__(256) void l2_partial(
    const float* __restrict__ Wa, int na, const float* __restrict__ Wb, int nb,
    const float* __restrict__ Wc, int nc, const float* __restrict__ Wd, int nd,
    float* __restrict__ part) {
  __shared__ float red[4];
  const int gid = blockIdx.x * 256 + threadIdx.x;
  const int stride = gridDim.x * 256;
  float s = 0.f;
  for (int i = gid; i < na; i += stride) { float v = Wa[i]; s = fmaf(v, v, s); }
  for (int i = gid; i < nb; i += stride) { float v = Wb[i]; s = fmaf(v, v, s); }
  for (int i = gid; i < nc; i += stride) { float v = Wc[i]; s = fmaf(v, v, s); }
  for (int i = gid; i < nd; i += stride) { float v = Wd[i]; s = fmaf(v, v, s); }
  const float tot = block_reduce_sum(s, red);
  if (threadIdx.x == 0) part[blockIdx.x] = tot;
}

// ---------------- final scalars ----------------
__global__ __launch_bounds__(256) void finals_kernel(
    const float* __restrict__ nll_b, const float* __restrict__ ce_b,
    const float* __restrict__ l2_part, int nparts, float* __restrict__ out4) {
  __shared__ float red[4];
  const int t = threadIdx.x;
  const float snll = block_reduce_sum(nll_b[t] + nll_b[t + 256], red);
  const float sce = block_reduce_sum(ce_b[t] + ce_b[t + 256], red);
  const float sl2 = block_reduce_sum((t < nparts) ? l2_part[t] : 0.f, red);
  if (t == 0) {
    const float nll = snll / (float)Bsz;
    const float marg = -sce / (float)Bsz;
    const float l2v = WDf * sl2;
    out4[0] = nll;
    out4[1] = marg;
    out4[2] = l2v;
    out4[3] = l2v + nll;
  }
}

// ---------------- launch ----------------
extern "C" void kernel_launch(void* const* d_in, const int* in_sizes, int n_in,
                              void* d_out, int out_size, void* d_ws, size_t ws_size,
                              hipStream_t stream) {
  const float* X = (const float*)d_in[0];
  const float* Y = (const float*)d_in[1];
  const float* noise = (const float*)d_in[2];
  const float* W1 = (const float*)d_in[3];
  const float* b1 = (const float*)d_in[4];
  const float* W2 = (const float*)d_in[5];
  const float* b2 = (const float*)d_in[6];
  const float* W3 = (const float*)d_in[7];
  const float* b3 = (const float*)d_in[8];
  const float* Wmu = (const float*)d_in[9];
  const float* bmu = (const float*)d_in[10];
  const float* rss = (const float*)d_in[11];

  float* ws = (float*)d_ws;
  // Region A (trunk temporaries; dead once logprob starts -> lp_part aliases it)
  float* h1 = ws;                       // 512*128   = 65536
  float* h2 = h1 + 65536;               // 512*256   = 131072
  float* feat = h2 + 131072;            // 512*256   = 131072
  float* nm = feat + 131072;            // 512*500   = 256000  (region A ends at 583680)
  float* lp_part = ws;                  // NCH*100*512 = 512000 (aliases A, written after A is dead)
  // Region B (live across the whole pipeline)
  float* B0 = ws + 583680;
  float* sqrtcov = B0;                  // 512
  float* rmuT = sqrtcov + 512;          // 500*512 = 256000
  float* yT = rmuT + 256000;            // 500*512 = 256000
  float* ce_b = yT + 256000;            // 512
  float* nll_b = ce_b + 512;            // 512
  float* l2_part = nll_b + 512;         // 128
  float* lp_sum = l2_part + 128;        // 100*512 = 51200   (total ~4.6 MB)

  float* out_prob = (float*)d_out;
  float* out4 = out_prob + (size_t)Bsz * Csz;

  cov_kernel<<<dim3(2), 256, 0, stream>>>(rss, sqrtcov);
  transpose_kernel<<<dim3(8, 8), 256, 0, stream>>>(Y, yT, Bsz, Csz);

  gemm_bias<true, false><<<dim3(2, 8), 256, 0, stream>>>(X, W1, b1, h1, 512, 128, 512, nullptr, nullptr);
  gemm_bias<true, false><<<dim3(4, 8), 256, 0, stream>>>(h1, W2, b2, h2, 512, 256, 128, nullptr, nullptr);
  gemm_bias<true, false><<<dim3(4, 8), 256, 0, stream>>>(h2, W3, b3, feat, 512, 256, 256, nullptr, nullptr);
  gemm_bias<false, true><<<dim3(8, 8), 256, 0, stream>>>(feat, Wmu, bmu, nm, 512, 500, 256, rmuT, sqrtcov);

  mu_post<<<dim3(512), 256, 0, stream>>>(nm, Y, out_prob, ce_b);

  logprob_kernel<<<dim3(NCH * 2 * Ssz), 256, 0, stream>>>(noise, rss, rmuT, yT, lp_part);
  lp_reduce<<<dim3(Ssz * Bsz / 256), 256, 0, stream>>>(lp_part, lp_sum);
  nll_kernel<<<dim3(2), 256, 0, stream>>>(lp_sum, nll_b);

  l2_partial<<<dim3(64), 256, 0, stream>>>(W1, 65536, W2, 32768, W3, 65536, Wmu, 128000, l2_part);
  finals_kernel<<<dim3(1), 256, 0, stream>>>(nll_b, ce_b, l2_part, 64, out4);
}

// Round 3
// 183.589 us; speedup vs baseline: 1.4708x; 1.3106x over previous
//
#include <hip/hip_runtime.h>
#include <cstddef>

#define EPS1f 1e-6f
#define WDf   1e-5f

constexpr int Bsz = 512, Fsz = 512, Csz = 500, Zsz = 64, Ssz = 100;
constexpr int NCH = 2;              // C-chunks (256 c's each, padded to 512)

typedef short bf16x8 __attribute__((ext_vector_type(8)));
typedef float f32x4 __attribute__((ext_vector_type(4)));

__device__ inline short f2bf(float f) {
  union { float f; unsigned u; } v; v.f = f;
  unsigned r = (v.u + 0x7fffu + ((v.u >> 16) & 1u)) >> 16;   // RNE
  return (short)r;
}

// ---------------- helpers ----------------
__device__ inline float block_reduce_sum(float v, float* red) {
  #pragma unroll
  for (int off = 32; off > 0; off >>= 1) v += __shfl_down(v, off, 64);
  const int lane = threadIdx.x & 63, wid = threadIdx.x >> 6;
  if (lane == 0) red[wid] = v;
  __syncthreads();
  float r = 0.f;
  if (threadIdx.x == 0) {
    const int nw = blockDim.x >> 6;
    for (int i = 0; i < nw; ++i) r += red[i];
  }
  __syncthreads();
  return r;   // valid in thread 0 only
}

// ---------------- generic 64x64 tile GEMM: out = act(A@W + bias) ----------------
template <bool RELU, bool MU>
__global__ __launch_bounds__(256) void gemm_bias(
    const float* __restrict__ A, const float* __restrict__ W,
    const float* __restrict__ bias, float* __restrict__ out,
    int M, int N, int K,
    float* __restrict__ rmuT, const float* __restrict__ sqrtcov) {
  __shared__ float As[16][68];   // [k][m], padded
  __shared__ float Ws[16][64];   // [k][n]
  const int bn = blockIdx.x * 64, bm = blockIdx.y * 64;
  const int tid = threadIdx.x;
  const int tn = tid & 15, tm = tid >> 4;
  const int arow = tid >> 2, ak = (tid & 3) * 4;
  const int wk = tid >> 4, wn = (tid & 15) * 4;
  float acc[4][4] = {};
  for (int kt = 0; kt < K; kt += 16) {
    float4 av = *reinterpret_cast<const float4*>(A + (size_t)(bm + arow) * K + kt + ak);
    float4 wv;
    const int nb = bn + wn;
    const float* wrow = W + (size_t)(kt + wk) * N;
    if (nb + 3 < N) {
      wv = *reinterpret_cast<const float4*>(wrow + nb);
    } else {
      wv.x = (nb + 0 < N) ? wrow[nb + 0] : 0.f;
      wv.y = (nb + 1 < N) ? wrow[nb + 1] : 0.f;
      wv.z = (nb + 2 < N) ? wrow[nb + 2] : 0.f;
      wv.w = (nb + 3 < N) ? wrow[nb + 3] : 0.f;
    }
    __syncthreads();
    As[ak + 0][arow] = av.x; As[ak + 1][arow] = av.y;
    As[ak + 2][arow] = av.z; As[ak + 3][arow] = av.w;
    *reinterpret_cast<float4*>(&Ws[wk][wn]) = wv;
    __syncthreads();
    #pragma unroll
    for (int k = 0; k < 16; ++k) {
      float4 a4 = *reinterpret_cast<const float4*>(&As[k][tm * 4]);
      float4 w4 = *reinterpret_cast<const float4*>(&Ws[k][tn * 4]);
      float ar[4] = {a4.x, a4.y, a4.z, a4.w};
      float wr[4] = {w4.x, w4.y, w4.z, w4.w};
      #pragma unroll
      for (int i = 0; i < 4; ++i) {
        #pragma unroll
        for (int j = 0; j < 4; ++j) acc[i][j] = fmaf(ar[i], wr[j], acc[i][j]);
      }
    }
  }
  #pragma unroll
  for (int j = 0; j < 4; ++j) {
    const int n = bn + tn * 4 + j;
    if (n >= N) continue;
    const float bv = bias[n];
    if (MU) {
      const float sc = sqrtcov[n];
      float vals[4];
      #pragma unroll
      for (int i = 0; i < 4; ++i) {
        const int m = bm + tm * 4 + i;
        const float v = acc[i][j] + bv;
        out[(size_t)m * N + n] = v;
        vals[i] = v * sc;
      }
      *reinterpret_cast<float4*>(rmuT + (size_t)n * Bsz + bm + tm * 4) =
          make_float4(vals[0], vals[1], vals[2], vals[3]);
    } else {
      #pragma unroll
      for (int i = 0; i < 4; ++i) {
        const int m = bm + tm * 4 + i;
        float v = acc[i][j] + bv;
        if (RELU) v = fmaxf(v, 0.f);
        out[(size_t)m * N + n] = v;
      }
    }
  }
}

// ---------------- prep: R -> bf16 (padded 512 rows) + sqrt(cov_diag) ----------------
__global__ __launch_bounds__(64) void rprep(const float* __restrict__ R,
                                            short* __restrict__ Rb,
                                            float* __restrict__ sqrtcov) {
  const int c = blockIdx.x;        // 0..511
  const int z = threadIdx.x;       // 0..63
  float v = (c < Csz) ? R[(size_t)c * Zsz + z] : 0.f;
  Rb[(size_t)c * Zsz + z] = f2bf(v);
  float s = v * v;
  #pragma unroll
  for (int off = 32; off > 0; off >>= 1) s += __shfl_xor(s, off, 64);
  if (z == 0 && c < Csz) sqrtcov[c] = sqrtf(1.f + s);
}

// ---------------- tiled transpose: in[rows][cols] -> out[cols][rows] ----------------
__global__ __launch_bounds__(256) void transpose_kernel(
    const float* __restrict__ in, float* __restrict__ out, int rows, int cols) {
  __shared__ float tile[64][65];
  const int c0 = blockIdx.x * 64;
  const int r0 = blockIdx.y * 64;
  const int tc = threadIdx.x & 63;
  const int tr4 = threadIdx.x >> 6;
  #pragma unroll
  for (int rr = tr4; rr < 64; rr += 4) {
    const int r = r0 + rr, c = c0 + tc;
    tile[rr][tc] = (c < cols && r < rows) ? in[(size_t)r * cols + c] : 0.f;
  }
  __syncthreads();
  #pragma unroll
  for (int cc = tr4; cc < 64; cc += 4) {
    const int c = c0 + cc, r = r0 + tc;
    if (c < cols && r < rows) out[(size_t)c * rows + r] = tile[tc][cc];
  }
}

// ---------------- mu epilogue: indiv_prob + CE row-sums ----------------
__global__ __launch_bounds__(256) void mu_post(
    const float* __restrict__ nm, const float* __restrict__ Y,
    float* __restrict__ out_prob, float* __restrict__ ce_b) {
  __shared__ float red[4];
  const int b = blockIdx.x;
  float ce = 0.f;
  for (int c = threadIdx.x; c < Csz; c += 256) {
    const float v = nm[(size_t)b * Csz + c];
    const float y = Y[(size_t)b * Csz + c];
    const float z = v * 1.70169f;
    const float sp = 1.f / (1.f + __expf(-z));
    const float p = fmaf(sp, 1.f - EPS1f, 0.5f * EPS1f);
    const float q = fmaf(1.f - sp, 1.f - EPS1f, 0.5f * EPS1f);
    out_prob[(size_t)b * Csz + c] = p;
    ce += __logf((y > 0.5f) ? p : q);
  }
  const float tot = block_reduce_sum(ce, red);
  if (threadIdx.x == 0) ce_b[b] = tot;
}

// ---------------- HOT: MFMA einsum + probit + log-likelihood ----------------
// wave: 16 sb-rows x 256 c's (16 c-tiles). block: 4 waves = 64 sb-rows. no barriers.
__global__ __launch_bounds__(256, 4) void logprob_mfma(
    const float* __restrict__ noise, const short* __restrict__ Rb,
    const float* __restrict__ rmuT, const float* __restrict__ yT,
    float* __restrict__ lp_part) {
  const int ch = blockIdx.x & 1;
  const int mb = blockIdx.x >> 1;            // 0..799
  const int wid = threadIdx.x >> 6;
  const int lane = threadIdx.x & 63;
  const int cl = lane & 15, grp = lane >> 4;
  const int sb0 = mb * 64 + wid * 16;        // 16 rows, all same s (16 | 512)
  const int s = sb0 >> 9;
  const int b0 = sb0 & 511;

  // A fragments: lane holds noise[sb0+cl][grp*8 + j] (k<32) and +32 (k>=32)
  const float* nrow = noise + (size_t)(sb0 + cl) * Zsz + grp * 8;
  const float4 n0 = *reinterpret_cast<const float4*>(nrow);
  const float4 n1 = *reinterpret_cast<const float4*>(nrow + 4);
  const float4 n2 = *reinterpret_cast<const float4*>(nrow + 32);
  const float4 n3 = *reinterpret_cast<const float4*>(nrow + 36);
  const bf16x8 a0 = { f2bf(n0.x), f2bf(n0.y), f2bf(n0.z), f2bf(n0.w),
                      f2bf(n1.x), f2bf(n1.y), f2bf(n1.z), f2bf(n1.w) };
  const bf16x8 a1 = { f2bf(n2.x), f2bf(n2.y), f2bf(n2.z), f2bf(n2.w),
                      f2bf(n3.x), f2bf(n3.y), f2bf(n3.z), f2bf(n3.w) };

  float lp0 = 0.f, lp1 = 0.f, lp2 = 0.f, lp3 = 0.f;
  const int cbase = ch * 256;
  #pragma unroll 2
  for (int t = 0; t < 16; ++t) {
    const int c = cbase + t * 16 + cl;
    const bf16x8 br0 = *reinterpret_cast<const bf16x8*>(Rb + (size_t)c * Zsz + grp * 8);
    const bf16x8 br1 = *reinterpret_cast<const bf16x8*>(Rb + (size_t)c * Zsz + 32 + grp * 8);
    f32x4 acc = {0.f, 0.f, 0.f, 0.f};
    acc = __builtin_amdgcn_mfma_f32_16x16x32_bf16(a0, br0, acc, 0, 0, 0);
    acc = __builtin_amdgcn_mfma_f32_16x16x32_bf16(a1, br1, acc, 0, 0, 0);
    const float4 rmu4 = *reinterpret_cast<const float4*>(rmuT + (size_t)c * Bsz + b0 + grp * 4);
    const float4 y4   = *reinterpret_cast<const float4*>(yT + (size_t)c * Bsz + b0 + grp * 4);
    const bool valid = (c < Csz);
    {
      const float x = acc[0] + rmu4.x, tt = x * fmaf(2.f, y4.x, -1.f);
      const float E = fmaf(0.5f * erfcf(tt * -0.70710678118654752f), 1.f - EPS1f, 0.5f * EPS1f);
      lp0 += valid ? __logf(E) : 0.f;
    }
    {
      const float x = acc[1] + rmu4.y, tt = x * fmaf(2.f, y4.y, -1.f);
      const float E = fmaf(0.5f * erfcf(tt * -0.70710678118654752f), 1.f - EPS1f, 0.5f * EPS1f);
      lp1 += valid ? __logf(E) : 0.f;
    }
    {
      const float x = acc[2] + rmu4.z, tt = x * fmaf(2.f, y4.z, -1.f);
      const float E = fmaf(0.5f * erfcf(tt * -0.70710678118654752f), 1.f - EPS1f, 0.5f * EPS1f);
      lp2 += valid ? __logf(E) : 0.f;
    }
    {
      const float x = acc[3] + rmu4.w, tt = x * fmaf(2.f, y4.w, -1.f);
      const float E = fmaf(0.5f * erfcf(tt * -0.70710678118654752f), 1.f - EPS1f, 0.5f * EPS1f);
      lp3 += valid ? __logf(E) : 0.f;
    }
  }
  // reduce over the 16 lanes (cl) sharing each (row-group, c-partition)
  #pragma unroll
  for (int off = 1; off < 16; off <<= 1) {
    lp0 += __shfl_xor(lp0, off, 64);
    lp1 += __shfl_xor(lp1, off, 64);
    lp2 += __shfl_xor(lp2, off, 64);
    lp3 += __shfl_xor(lp3, off, 64);
  }
  if (cl == 0) {
    float* dst = lp_part + ((size_t)(ch * Ssz + s)) * Bsz + b0 + grp * 4;
    dst[0] = lp0; dst[1] = lp1; dst[2] = lp2; dst[3] = lp3;
  }
}

// ---------------- per-b online log-sum-exp over S (chunk-sum fused) ----------------
__global__ __launch_bounds__(64) void nll_kernel(const float* __restrict__ lp_part,
                                                 float* __restrict__ nll_b) {
  const int b = blockIdx.x * 64 + threadIdx.x;
  float m = -3.0e38f, se = 0.f;
  for (int s = 0; s < Ssz; ++s) {
    const float v = lp_part[(size_t)s * Bsz + b] + lp_part[(size_t)(Ssz + s) * Bsz + b];
    const float mn = fmaxf(m, v);
    se = se * __expf(m - mn) + __expf(v - mn);
    m = mn;
  }
  nll_b[b] = -__logf(se * (1.f / (float)Ssz)) - m;
}

// ---------------- L2 partials ----------------
__global__ __launch_bounds__(256) void l2_partial(
    const float* __restrict__ Wa, int na, const float* __restrict__ Wb, int nb,
    const float* __restrict__ Wc, int nc, const float* __restrict__ Wd, int nd,
    float* __restrict__ part) {
  __shared__ float red[4];
  const int gid = blockIdx.x * 256 + threadIdx.x;
  const int stride = gridDim.x * 256;
  float s = 0.f;
  for (int i = gid; i < na; i += stride) { float v = Wa[i]; s = fmaf(v, v, s); }
  for (int i = gid; i < nb; i += stride) { float v = Wb[i]; s = fmaf(v, v, s); }
  for (int i = gid; i < nc; i += stride) { float v = Wc[i]; s = fmaf(v, v, s); }
  for (int i = gid; i < nd; i += stride) { float v = Wd[i]; s = fmaf(v, v, s); }
  const float tot = block_reduce_sum(s, red);
  if (threadIdx.x == 0) part[blockIdx.x] = tot;
}

// ---------------- final scalars ----------------
__global__ __launch_bounds__(256) void finals_kernel(
    const float* __restrict__ nll_b, const float* __restrict__ ce_b,
    const float* __restrict__ l2_part, int nparts, float* __restrict__ out4) {
  __shared__ float red[4];
  const int t = threadIdx.x;
  const float snll = block_reduce_sum(nll_b[t] + nll_b[t + 256], red);
  const float sce = block_reduce_sum(ce_b[t] + ce_b[t + 256], red);
  const float sl2 = block_reduce_sum((t < nparts) ? l2_part[t] : 0.f, red);
  if (t == 0) {
    const float nll = snll / (float)Bsz;
    const float marg = -sce / (float)Bsz;
    const float l2v = WDf * sl2;
    out4[0] = nll;
    out4[1] = marg;
    out4[2] = l2v;
    out4[3] = l2v + nll;
  }
}

// ---------------- launch ----------------
extern "C" void kernel_launch(void* const* d_in, const int* in_sizes, int n_in,
                              void* d_out, int out_size, void* d_ws, size_t ws_size,
                              hipStream_t stream) {
  const float* X = (const float*)d_in[0];
  const float* Y = (const float*)d_in[1];
  const float* noise = (const float*)d_in[2];
  const float* W1 = (const float*)d_in[3];
  const float* b1 = (const float*)d_in[4];
  const float* W2 = (const float*)d_in[5];
  const float* b2 = (const float*)d_in[6];
  const float* W3 = (const float*)d_in[7];
  const float* b3 = (const float*)d_in[8];
  const float* Wmu = (const float*)d_in[9];
  const float* bmu = (const float*)d_in[10];
  const float* rss = (const float*)d_in[11];

  float* ws = (float*)d_ws;
  // Region A (trunk temporaries; dead once logprob starts -> lp_part aliases it)
  float* h1 = ws;                        // 512*128   = 65536
  float* h2 = h1 + 65536;                // 512*256   = 131072
  float* feat = h2 + 131072;             // 512*256   = 131072
  float* nm = feat + 131072;             // 512*500   = 256000  (A ends at 583680)
  float* lp_part = ws;                   // 2*100*512 = 102400  (aliases A)
  // Region B (live across the pipeline)
  float* B0 = ws + 583680;
  float* sqrtcov = B0;                   // 512
  float* rmuT = sqrtcov + 512;           // 512*512 = 262144 (rows 500..511 unwritten, masked)
  float* yT = rmuT + 262144;             // 512*512 = 262144 (rows 500..511 unwritten, masked)
  float* ce_b = yT + 262144;             // 512
  float* nll_b = ce_b + 512;             // 512
  float* l2_part = nll_b + 512;          // 128
  short* Rb = (short*)(l2_part + 128);   // 512*64 bf16 = 16384 float-equiv

  float* out_prob = (float*)d_out;
  float* out4 = out_prob + (size_t)Bsz * Csz;

  rprep<<<dim3(512), 64, 0, stream>>>(rss, Rb, sqrtcov);
  transpose_kernel<<<dim3(8, 8), 256, 0, stream>>>(Y, yT, Bsz, Csz);

  gemm_bias<true, false><<<dim3(2, 8), 256, 0, stream>>>(X, W1, b1, h1, 512, 128, 512, nullptr, nullptr);
  gemm_bias<true, false><<<dim3(4, 8), 256, 0, stream>>>(h1, W2, b2, h2, 512, 256, 128, nullptr, nullptr);
  gemm_bias<true, false><<<dim3(4, 8), 256, 0, stream>>>(h2, W3, b3, feat, 512, 256, 256, nullptr, nullptr);
  gemm_bias<false, true><<<dim3(8, 8), 256, 0, stream>>>(feat, Wmu, bmu, nm, 512, 500, 256, rmuT, sqrtcov);

  mu_post<<<dim3(512), 256, 0, stream>>>(nm, Y, out_prob, ce_b);

  logprob_mfma<<<dim3(800 * NCH), 256, 0, stream>>>(noise, Rb, rmuT, yT, lp_part);
  nll_kernel<<<dim3(8), 64, 0, stream>>>(lp_part, nll_b);

  l2_partial<<<dim3(64), 256, 0, stream>>>(W1, 65536, W2, 32768, W3, 65536, Wmu, 128000, l2_part);
  finals_kernel<<<dim3(1), 256, 0, stream>>>(nll_b, ce_b, l2_part, 64, out4);
}

// Round 4
// 138.360 us; speedup vs baseline: 1.9516x; 1.3269x over previous
//
#include <hip/hip_runtime.h>
#include <cstddef>

#define EPS1f 1e-6f
#define WDf   1e-5f

constexpr int Bsz = 512, Fsz = 512, Csz = 500, Zsz = 64, Ssz = 100;
constexpr int NCH = 2;              // C-chunks for logprob (256 c's each)

typedef short bf16x8 __attribute__((ext_vector_type(8)));
typedef float f32x4 __attribute__((ext_vector_type(4)));

__device__ inline short f2bf(float f) {
  union { float f; unsigned u; } v; v.f = f;
  unsigned r = (v.u + 0x7fffu + ((v.u >> 16) & 1u)) >> 16;   // RNE
  return (short)r;
}

// log( Phi(t)*(1-eps) + eps/2 )  via A&S 7.1.26 erfc approx (|err|<=1.5e-7)
__device__ inline float log_probit(float t) {
  const float u = t * -0.70710678118654752f;      // Phi(t) = 0.5*erfc(u)
  const float au = fabsf(u);
  const float s = 1.f / fmaf(0.3275911f, au, 1.f);
  float p = fmaf(1.061405429f, s, -1.453152027f);
  p = fmaf(p, s, 1.421413741f);
  p = fmaf(p, s, -0.284496736f);
  p = fmaf(p, s, 0.254829592f);
  p = p * s;
  const float e = __expf(-au * au);
  const float f = p * e;                           // erfc(au), au>=0
  const float erfc_u = (u < 0.f) ? (2.f - f) : f;
  const float E = fmaf(0.5f * erfc_u, 1.f - EPS1f, 0.5f * EPS1f);
  return __logf(E);
}

// ---------------- helpers ----------------
__device__ inline float block_reduce_sum(float v, float* red) {
  #pragma unroll
  for (int off = 32; off > 0; off >>= 1) v += __shfl_down(v, off, 64);
  const int lane = threadIdx.x & 63, wid = threadIdx.x >> 6;
  if (lane == 0) red[wid] = v;
  __syncthreads();
  float r = 0.f;
  if (threadIdx.x == 0) {
    const int nw = blockDim.x >> 6;
    for (int i = 0; i < nw; ++i) r += red[i];
  }
  __syncthreads();
  return r;   // valid in thread 0 only
}

// ---------------- 32x32-tile double-buffered GEMM: out = act(A@W + bias) ----------------
template <bool RELU>
__global__ __launch_bounds__(256) void gemm32(
    const float* __restrict__ A, const float* __restrict__ W,
    const float* __restrict__ bias, float* __restrict__ out,
    int M, int N, int K) {
  __shared__ float As[2][32][36];   // [buf][k][m]
  __shared__ float Ws[2][32][36];   // [buf][k][n]
  const int tid = threadIdx.x;
  const int bn = blockIdx.x * 32, bm = blockIdx.y * 32;
  const int sm = tid >> 3, sk4 = (tid & 7) * 4;   // A staging
  const int sk = tid >> 3, sn4 = (tid & 7) * 4;   // W staging
  const int tn = tid & 15, tm = tid >> 4;

  auto loadW = [&](int kt, float4& wv) {
    const float* wrow = W + (size_t)(kt + sk) * N;
    const int nn = bn + sn4;
    if (nn + 3 < N) wv = *reinterpret_cast<const float4*>(wrow + nn);
    else {
      wv.x = (nn + 0 < N) ? wrow[nn + 0] : 0.f;
      wv.y = (nn + 1 < N) ? wrow[nn + 1] : 0.f;
      wv.z = (nn + 2 < N) ? wrow[nn + 2] : 0.f;
      wv.w = (nn + 3 < N) ? wrow[nn + 3] : 0.f;
    }
  };

  // prologue: stage kt=0 into buf 0
  {
    float4 av = *reinterpret_cast<const float4*>(A + (size_t)(bm + sm) * K + sk4);
    float4 wv; loadW(0, wv);
    As[0][sk4 + 0][sm] = av.x; As[0][sk4 + 1][sm] = av.y;
    As[0][sk4 + 2][sm] = av.z; As[0][sk4 + 3][sm] = av.w;
    *reinterpret_cast<float4*>(&Ws[0][sk][sn4]) = wv;
  }
  __syncthreads();

  float acc[2][2] = {};
  int pb = 0;
  for (int kt = 0; kt < K; kt += 32) {
    const bool more = (kt + 32) < K;
    float4 av2, wv2;
    if (more) {
      av2 = *reinterpret_cast<const float4*>(A + (size_t)(bm + sm) * K + kt + 32 + sk4);
      loadW(kt + 32, wv2);
    }
    #pragma unroll
    for (int k = 0; k < 32; ++k) {
      const float2 a = *reinterpret_cast<const float2*>(&As[pb][k][tm * 2]);
      const float2 w = *reinterpret_cast<const float2*>(&Ws[pb][k][tn * 2]);
      acc[0][0] = fmaf(a.x, w.x, acc[0][0]);
      acc[0][1] = fmaf(a.x, w.y, acc[0][1]);
      acc[1][0] = fmaf(a.y, w.x, acc[1][0]);
      acc[1][1] = fmaf(a.y, w.y, acc[1][1]);
    }
    if (more) {
      const int nb = pb ^ 1;
      As[nb][sk4 + 0][sm] = av2.x; As[nb][sk4 + 1][sm] = av2.y;
      As[nb][sk4 + 2][sm] = av2.z; As[nb][sk4 + 3][sm] = av2.w;
      *reinterpret_cast<float4*>(&Ws[nb][sk][sn4]) = wv2;
      __syncthreads();
      pb = nb;
    }
  }
  #pragma unroll
  for (int j = 0; j < 2; ++j) {
    const int n = bn + tn * 2 + j;
    if (n >= N) continue;
    const float bv = bias[n];
    #pragma unroll
    for (int i = 0; i < 2; ++i) {
      const int m = bm + tm * 2 + i;
      float v = acc[i][j] + bv;
      if (RELU) v = fmaxf(v, 0.f);
      out[(size_t)m * N + n] = v;
    }
  }
}

// ---------------- MU GEMM: feat@Wmu+bmu -> indiv_prob, CE partials, rmuT ----------------
__global__ __launch_bounds__(256) void gemm32_mu(
    const float* __restrict__ A, const float* __restrict__ W,
    const float* __restrict__ bias, const float* __restrict__ Y,
    const float* __restrict__ sqrtcov,
    float* __restrict__ out_prob, float* __restrict__ rmuT,
    float* __restrict__ ce_part, int M, int N, int K) {
  __shared__ float As[2][32][36];
  __shared__ float Ws[2][32][36];
  const int tid = threadIdx.x;
  const int bn = blockIdx.x * 32, bm = blockIdx.y * 32;
  const int sm = tid >> 3, sk4 = (tid & 7) * 4;
  const int sk = tid >> 3, sn4 = (tid & 7) * 4;
  const int tn = tid & 15, tm = tid >> 4;

  auto loadW = [&](int kt, float4& wv) {
    const float* wrow = W + (size_t)(kt + sk) * N;
    const int nn = bn + sn4;
    if (nn + 3 < N) wv = *reinterpret_cast<const float4*>(wrow + nn);
    else {
      wv.x = (nn + 0 < N) ? wrow[nn + 0] : 0.f;
      wv.y = (nn + 1 < N) ? wrow[nn + 1] : 0.f;
      wv.z = (nn + 2 < N) ? wrow[nn + 2] : 0.f;
      wv.w = (nn + 3 < N) ? wrow[nn + 3] : 0.f;
    }
  };
  {
    float4 av = *reinterpret_cast<const float4*>(A + (size_t)(bm + sm) * K + sk4);
    float4 wv; loadW(0, wv);
    As[0][sk4 + 0][sm] = av.x; As[0][sk4 + 1][sm] = av.y;
    As[0][sk4 + 2][sm] = av.z; As[0][sk4 + 3][sm] = av.w;
    *reinterpret_cast<float4*>(&Ws[0][sk][sn4]) = wv;
  }
  __syncthreads();
  float acc[2][2] = {};
  int pb = 0;
  for (int kt = 0; kt < K; kt += 32) {
    const bool more = (kt + 32) < K;
    float4 av2, wv2;
    if (more) {
      av2 = *reinterpret_cast<const float4*>(A + (size_t)(bm + sm) * K + kt + 32 + sk4);
      loadW(kt + 32, wv2);
    }
    #pragma unroll
    for (int k = 0; k < 32; ++k) {
      const float2 a = *reinterpret_cast<const float2*>(&As[pb][k][tm * 2]);
      const float2 w = *reinterpret_cast<const float2*>(&Ws[pb][k][tn * 2]);
      acc[0][0] = fmaf(a.x, w.x, acc[0][0]);
      acc[0][1] = fmaf(a.x, w.y, acc[0][1]);
      acc[1][0] = fmaf(a.y, w.x, acc[1][0]);
      acc[1][1] = fmaf(a.y, w.y, acc[1][1]);
    }
    if (more) {
      const int nb = pb ^ 1;
      As[nb][sk4 + 0][sm] = av2.x; As[nb][sk4 + 1][sm] = av2.y;
      As[nb][sk4 + 2][sm] = av2.z; As[nb][sk4 + 3][sm] = av2.w;
      *reinterpret_cast<float4*>(&Ws[nb][sk][sn4]) = wv2;
      __syncthreads();
      pb = nb;
    }
  }
  // epilogue: prob + ce + rmuT
  float ce2[2] = {0.f, 0.f};
  #pragma unroll
  for (int i = 0; i < 2; ++i) {
    const int m = bm + tm * 2 + i;
    #pragma unroll
    for (int j = 0; j < 2; ++j) {
      const int n = bn + tn * 2 + j;
      if (n < N) {
        const float v = acc[i][j] + bias[n];
        const float sp = 1.f / (1.f + __expf(-1.70169f * v));
        const float p = fmaf(sp, 1.f - EPS1f, 0.5f * EPS1f);
        const float q = fmaf(1.f - sp, 1.f - EPS1f, 0.5f * EPS1f);
        const float y = Y[(size_t)m * N + n];
        out_prob[(size_t)m * N + n] = p;
        ce2[i] += __logf((y > 0.5f) ? p : q);
        rmuT[(size_t)n * Bsz + m] = v * sqrtcov[n];
      }
    }
  }
  #pragma unroll
  for (int off = 1; off < 16; off <<= 1) {
    ce2[0] += __shfl_xor(ce2[0], off, 64);
    ce2[1] += __shfl_xor(ce2[1], off, 64);
  }
  if (tn == 0) {
    const int m0 = bm + tm * 2;
    ce_part[(size_t)blockIdx.x * Bsz + m0] = ce2[0];
    ce_part[(size_t)blockIdx.x * Bsz + m0 + 1] = ce2[1];
  }
}

// ---------------- prep: R -> bf16 (padded 512 rows) + sqrt(cov_diag) ----------------
__global__ __launch_bounds__(64) void rprep(const float* __restrict__ R,
                                            short* __restrict__ Rb,
                                            float* __restrict__ sqrtcov) {
  const int c = blockIdx.x;        // 0..511
  const int z = threadIdx.x;       // 0..63
  float v = (c < Csz) ? R[(size_t)c * Zsz + z] : 0.f;
  Rb[(size_t)c * Zsz + z] = f2bf(v);
  float s = v * v;
  #pragma unroll
  for (int off = 32; off > 0; off >>= 1) s += __shfl_xor(s, off, 64);
  if (z == 0 && c < Csz) sqrtcov[c] = sqrtf(1.f + s);
}

// ---------------- tiled transpose: in[rows][cols] -> out[cols][rows] ----------------
__global__ __launch_bounds__(256) void transpose_kernel(
    const float* __restrict__ in, float* __restrict__ out, int rows, int cols) {
  __shared__ float tile[64][65];
  const int c0 = blockIdx.x * 64;
  const int r0 = blockIdx.y * 64;
  const int tc = threadIdx.x & 63;
  const int tr4 = threadIdx.x >> 6;
  #pragma unroll
  for (int rr = tr4; rr < 64; rr += 4) {
    const int r = r0 + rr, c = c0 + tc;
    tile[rr][tc] = (c < cols && r < rows) ? in[(size_t)r * cols + c] : 0.f;
  }
  __syncthreads();
  #pragma unroll
  for (int cc = tr4; cc < 64; cc += 4) {
    const int c = c0 + cc, r = r0 + tc;
    if (c < cols && r < rows) out[(size_t)c * rows + r] = tile[tc][cc];
  }
}

// ---------------- HOT: MFMA einsum + probit + log-likelihood ----------------
__global__ __launch_bounds__(256, 4) void logprob_mfma(
    const float* __restrict__ noise, const short* __restrict__ Rb,
    const float* __restrict__ rmuT, const float* __restrict__ yT,
    float* __restrict__ lp_part) {
  const int ch = blockIdx.x & 1;
  const int mb = blockIdx.x >> 1;            // 0..799
  const int wid = threadIdx.x >> 6;
  const int lane = threadIdx.x & 63;
  const int cl = lane & 15, grp = lane >> 4;
  const int sb0 = mb * 64 + wid * 16;        // 16 rows, all same s
  const int s = sb0 >> 9;
  const int b0 = sb0 & 511;

  const float* nrow = noise + (size_t)(sb0 + cl) * Zsz + grp * 8;
  const float4 n0 = *reinterpret_cast<const float4*>(nrow);
  const float4 n1 = *reinterpret_cast<const float4*>(nrow + 4);
  const float4 n2 = *reinterpret_cast<const float4*>(nrow + 32);
  const float4 n3 = *reinterpret_cast<const float4*>(nrow + 36);
  const bf16x8 a0 = { f2bf(n0.x), f2bf(n0.y), f2bf(n0.z), f2bf(n0.w),
                      f2bf(n1.x), f2bf(n1.y), f2bf(n1.z), f2bf(n1.w) };
  const bf16x8 a1 = { f2bf(n2.x), f2bf(n2.y), f2bf(n2.z), f2bf(n2.w),
                      f2bf(n3.x), f2bf(n3.y), f2bf(n3.z), f2bf(n3.w) };

  float lp0 = 0.f, lp1 = 0.f, lp2 = 0.f, lp3 = 0.f;
  const int cbase = ch * 256;
  #pragma unroll 2
  for (int t = 0; t < 16; ++t) {
    const int c = cbase + t * 16 + cl;
    const bf16x8 br0 = *reinterpret_cast<const bf16x8*>(Rb + (size_t)c * Zsz + grp * 8);
    const bf16x8 br1 = *reinterpret_cast<const bf16x8*>(Rb + (size_t)c * Zsz + 32 + grp * 8);
    f32x4 acc = {0.f, 0.f, 0.f, 0.f};
    acc = __builtin_amdgcn_mfma_f32_16x16x32_bf16(a0, br0, acc, 0, 0, 0);
    acc = __builtin_amdgcn_mfma_f32_16x16x32_bf16(a1, br1, acc, 0, 0, 0);
    const float4 rmu4 = *reinterpret_cast<const float4*>(rmuT + (size_t)c * Bsz + b0 + grp * 4);
    const float4 y4   = *reinterpret_cast<const float4*>(yT + (size_t)c * Bsz + b0 + grp * 4);
    const bool valid = (c < Csz);
    lp0 += valid ? log_probit((acc[0] + rmu4.x) * fmaf(2.f, y4.x, -1.f)) : 0.f;
    lp1 += valid ? log_probit((acc[1] + rmu4.y) * fmaf(2.f, y4.y, -1.f)) : 0.f;
    lp2 += valid ? log_probit((acc[2] + rmu4.z) * fmaf(2.f, y4.z, -1.f)) : 0.f;
    lp3 += valid ? log_probit((acc[3] + rmu4.w) * fmaf(2.f, y4.w, -1.f)) : 0.f;
  }
  #pragma unroll
  for (int off = 1; off < 16; off <<= 1) {
    lp0 += __shfl_xor(lp0, off, 64);
    lp1 += __shfl_xor(lp1, off, 64);
    lp2 += __shfl_xor(lp2, off, 64);
    lp3 += __shfl_xor(lp3, off, 64);
  }
  if (cl == 0) {
    float* dst = lp_part + ((size_t)(ch * Ssz + s)) * Bsz + b0 + grp * 4;
    dst[0] = lp0; dst[1] = lp1; dst[2] = lp2; dst[3] = lp3;
  }
}

// ---------------- per-b log-sum-exp over S (4-way s-parallel) ----------------
__global__ __launch_bounds__(256) void nll_kernel(const float* __restrict__ lp_part,
                                                  float* __restrict__ nll_b) {
  __shared__ float sm[4][64], sse[4][64];
  const int bl = threadIdx.x & 63;
  const int sc = threadIdx.x >> 6;           // 0..3, 25 s each
  const int b = blockIdx.x * 64 + bl;
  float m = -3.0e38f, se = 0.f;
  for (int s = sc * 25; s < sc * 25 + 25; ++s) {
    const float v = lp_part[(size_t)s * Bsz + b] + lp_part[(size_t)(Ssz + s) * Bsz + b];
    const float mn = fmaxf(m, v);
    se = se * __expf(m - mn) + __expf(v - mn);
    m = mn;
  }
  sm[sc][bl] = m; sse[sc][bl] = se;
  __syncthreads();
  if (sc == 0) {
    float M = sm[0][bl];
    #pragma unroll
    for (int i = 1; i < 4; ++i) M = fmaxf(M, sm[i][bl]);
    float SE = 0.f;
    #pragma unroll
    for (int i = 0; i < 4; ++i) SE += sse[i][bl] * __expf(sm[i][bl] - M);
    nll_b[b] = -__logf(SE * (1.f / (float)Ssz)) - M;
  }
}

// ---------------- L2 partials ----------------
__global__ __launch_bounds__(256) void l2_partial(
    const float* __restrict__ Wa, int na, const float* __restrict__ Wb, int nb,
    const float* __restrict__ Wc, int nc, const float* __restrict__ Wd, int nd,
    float* __restrict__ part) {
  __shared__ float red[4];
  const int gid = blockIdx.x * 256 + threadIdx.x;
  const int stride = gridDim.x * 256;
  float s = 0.f;
  for (int i = gid; i < na; i += stride) { float v = Wa[i]; s = fmaf(v, v, s); }
  for (int i = gid; i < nb; i += stride) { float v = Wb[i]; s = fmaf(v, v, s); }
  for (int i = gid; i < nc; i += stride) { float v = Wc[i]; s = fmaf(v, v, s); }
  for (int i = gid; i < nd; i += stride) { float v = Wd[i]; s = fmaf(v, v, s); }
  const float tot = block_reduce_sum(s, red);
  if (threadIdx.x == 0) part[blockIdx.x] = tot;
}

// ---------------- final scalars ----------------
__global__ __launch_bounds__(256) void finals_kernel(
    const float* __restrict__ nll_b, const float* __restrict__ ce_part,
    const float* __restrict__ l2_part, int nparts, float* __restrict__ out4) {
  __shared__ float red[4];
  const int t = threadIdx.x;
  const float snll = block_reduce_sum(nll_b[t] + nll_b[t + 256], red);
  float ce = 0.f;
  #pragma unroll
  for (int i = 0; i < 32; ++i) ce += ce_part[i * 256 + t];   // 16*512 entries
  const float sce = block_reduce_sum(ce, red);
  const float sl2 = block_reduce_sum((t < nparts) ? l2_part[t] : 0.f, red);
  if (t == 0) {
    const float nll = snll / (float)Bsz;
    const float marg = -sce / (float)Bsz;
    const float l2v = WDf * sl2;
    out4[0] = nll;
    out4[1] = marg;
    out4[2] = l2v;
    out4[3] = l2v + nll;
  }
}

// ---------------- launch ----------------
extern "C" void kernel_launch(void* const* d_in, const int* in_sizes, int n_in,
                              void* d_out, int out_size, void* d_ws, size_t ws_size,
                              hipStream_t stream) {
  const float* X = (const float*)d_in[0];
  const float* Y = (const float*)d_in[1];
  const float* noise = (const float*)d_in[2];
  const float* W1 = (const float*)d_in[3];
  const float* b1 = (const float*)d_in[4];
  const float* W2 = (const float*)d_in[5];
  const float* b2 = (const float*)d_in[6];
  const float* W3 = (const float*)d_in[7];
  const float* b3 = (const float*)d_in[8];
  const float* Wmu = (const float*)d_in[9];
  const float* bmu = (const float*)d_in[10];
  const float* rss = (const float*)d_in[11];

  float* ws = (float*)d_ws;
  // Region A: trunk temporaries (dead once logprob starts -> lp_part aliases)
  float* h1 = ws;                        // 512*128   = 65536
  float* h2 = h1 + 65536;                // 512*256   = 131072
  float* feat = h2 + 131072;             // 512*256   = 131072  (A ends at 327680)
  float* lp_part = ws;                   // 2*100*512 = 102400  (aliases A)
  // Region B: live across pipeline
  float* B0 = ws + 327680;
  float* sqrtcov = B0;                   // 512
  float* rmuT = sqrtcov + 512;           // 512*512 = 262144 (rows 500..511 unwritten, masked)
  float* yT = rmuT + 262144;             // 512*512 = 262144
  float* ce_part = yT + 262144;          // 16*512 = 8192
  float* nll_b = ce_part + 8192;         // 512
  float* l2_part = nll_b + 512;          // 128
  short* Rb = (short*)(l2_part + 128);   // 512*64 bf16

  float* out_prob = (float*)d_out;
  float* out4 = out_prob + (size_t)Bsz * Csz;

  rprep<<<dim3(512), 64, 0, stream>>>(rss, Rb, sqrtcov);
  transpose_kernel<<<dim3(8, 8), 256, 0, stream>>>(Y, yT, Bsz, Csz);

  gemm32<true><<<dim3(4, 16), 256, 0, stream>>>(X, W1, b1, h1, 512, 128, 512);
  gemm32<true><<<dim3(8, 16), 256, 0, stream>>>(h1, W2, b2, h2, 512, 256, 128);
  gemm32<true><<<dim3(8, 16), 256, 0, stream>>>(h2, W3, b3, feat, 512, 256, 256);
  gemm32_mu<<<dim3(16, 16), 256, 0, stream>>>(feat, Wmu, bmu, Y, sqrtcov,
                                              out_prob, rmuT, ce_part, 512, 500, 256);

  logprob_mfma<<<dim3(800 * NCH), 256, 0, stream>>>(noise, Rb, rmuT, yT, lp_part);
  nll_kernel<<<dim3(8), 256, 0, stream>>>(lp_part, nll_b);

  l2_partial<<<dim3(64), 256, 0, stream>>>(W1, 65536, W2, 32768, W3, 65536, Wmu, 128000, l2_part);
  finals_kernel<<<dim3(1), 256, 0, stream>>>(nll_b, ce_part, l2_part, 64, out4);
}

// Round 5
// 105.369 us; speedup vs baseline: 2.5627x; 1.3131x over previous
//
#include <hip/hip_runtime.h>
#include <cstddef>

#define EPS1f 1e-6f
#define WDf   1e-5f

constexpr int Bsz = 512, Fsz = 512, Csz = 500, Zsz = 64, Ssz = 100;

typedef short bf16x8 __attribute__((ext_vector_type(8)));
typedef float f32x4 __attribute__((ext_vector_type(4)));

__device__ inline short f2bf(float f) {
  union { float f; unsigned u; } v; v.f = f;
  unsigned r = (v.u + 0x7fffu + ((v.u >> 16) & 1u)) >> 16;   // RNE
  return (short)r;
}

// log( Phi(t)*(1-eps) + eps/2 )  via A&S 7.1.26 erfc approx (|err|<=1.5e-7)
__device__ inline float log_probit(float t) {
  const float u = t * -0.70710678118654752f;      // Phi(t) = 0.5*erfc(u)
  const float au = fabsf(u);
  const float s = 1.f / fmaf(0.3275911f, au, 1.f);
  float p = fmaf(1.061405429f, s, -1.453152027f);
  p = fmaf(p, s, 1.421413741f);
  p = fmaf(p, s, -0.284496736f);
  p = fmaf(p, s, 0.254829592f);
  p = p * s;
  const float e = __expf(-au * au);
  const float f = p * e;                           // erfc(au), au>=0
  const float erfc_u = (u < 0.f) ? (2.f - f) : f;
  const float E = fmaf(0.5f * erfc_u, 1.f - EPS1f, 0.5f * EPS1f);
  return __logf(E);
}

// ---------------- helpers ----------------
__device__ inline float block_reduce_sum(float v, float* red) {
  #pragma unroll
  for (int off = 32; off > 0; off >>= 1) v += __shfl_down(v, off, 64);
  const int lane = threadIdx.x & 63, wid = threadIdx.x >> 6;
  if (lane == 0) red[wid] = v;
  __syncthreads();
  float r = 0.f;
  if (threadIdx.x == 0) {
    const int nw = blockDim.x >> 6;
    for (int i = 0; i < nw; ++i) r += red[i];
  }
  __syncthreads();
  return r;   // valid in thread 0 only
}

// ---------------- noise -> bf16 MFMA-fragment layout ----------------
// frag unit u = ((s*32 + bt)*2 + f)*64 + lane ; lane=(cl,grp): holds
// noise[s][bt*16+cl][f*32 + grp*8 + 0..7]
__global__ __launch_bounds__(256) void nprep(const float* __restrict__ noise,
                                             short* __restrict__ nfB) {
  const int g = blockIdx.x * 256 + threadIdx.x;    // 100*32*64 = 204800
  const int s = g >> 11;
  const int r = g & 2047;
  const int bt = r >> 6;
  const int ln = r & 63;
  const int cl = ln & 15, grp = ln >> 4;
  const float* src = noise + ((size_t)(s * 512 + bt * 16 + cl) * 64 + grp * 8);
  const float4 a = *reinterpret_cast<const float4*>(src);
  const float4 b = *reinterpret_cast<const float4*>(src + 4);
  const float4 c = *reinterpret_cast<const float4*>(src + 32);
  const float4 d = *reinterpret_cast<const float4*>(src + 36);
  bf16x8* dst = reinterpret_cast<bf16x8*>(nfB);
  const int u = (s * 32 + bt) * 128 + ln;
  dst[u]      = bf16x8{ f2bf(a.x), f2bf(a.y), f2bf(a.z), f2bf(a.w),
                        f2bf(b.x), f2bf(b.y), f2bf(b.z), f2bf(b.w) };
  dst[u + 64] = bf16x8{ f2bf(c.x), f2bf(c.y), f2bf(c.z), f2bf(c.w),
                        f2bf(d.x), f2bf(d.y), f2bf(d.z), f2bf(d.w) };
}

// ---------------- prep: R -> bf16 (padded 512 rows) + sqrt(cov_diag) ----------------
__global__ __launch_bounds__(64) void rprep(const float* __restrict__ R,
                                            short* __restrict__ Rb,
                                            float* __restrict__ sqrtcov) {
  const int c = blockIdx.x;        // 0..511
  const int z = threadIdx.x;       // 0..63
  float v = (c < Csz) ? R[(size_t)c * Zsz + z] : 0.f;
  Rb[(size_t)c * Zsz + z] = f2bf(v);
  float s = v * v;
  #pragma unroll
  for (int off = 32; off > 0; off >>= 1) s += __shfl_xor(s, off, 64);
  if (z == 0 && c < Csz) sqrtcov[c] = sqrtf(1.f + s);
}

// ---------------- 32x32-tile double-buffered GEMM: out = act(A@W + bias) ----------------
template <bool RELU>
__global__ __launch_bounds__(256) void gemm32(
    const float* __restrict__ A, const float* __restrict__ W,
    const float* __restrict__ bias, float* __restrict__ out,
    int M, int N, int K) {
  __shared__ float As[2][32][36];
  __shared__ float Ws[2][32][36];
  const int tid = threadIdx.x;
  const int bn = blockIdx.x * 32, bm = blockIdx.y * 32;
  const int sm = tid >> 3, sk4 = (tid & 7) * 4;
  const int sk = tid >> 3, sn4 = (tid & 7) * 4;
  const int tn = tid & 15, tm = tid >> 4;

  auto loadW = [&](int kt, float4& wv) {
    const float* wrow = W + (size_t)(kt + sk) * N;
    const int nn = bn + sn4;
    if (nn + 3 < N) wv = *reinterpret_cast<const float4*>(wrow + nn);
    else {
      wv.x = (nn + 0 < N) ? wrow[nn + 0] : 0.f;
      wv.y = (nn + 1 < N) ? wrow[nn + 1] : 0.f;
      wv.z = (nn + 2 < N) ? wrow[nn + 2] : 0.f;
      wv.w = (nn + 3 < N) ? wrow[nn + 3] : 0.f;
    }
  };
  {
    float4 av = *reinterpret_cast<const float4*>(A + (size_t)(bm + sm) * K + sk4);
    float4 wv; loadW(0, wv);
    As[0][sk4 + 0][sm] = av.x; As[0][sk4 + 1][sm] = av.y;
    As[0][sk4 + 2][sm] = av.z; As[0][sk4 + 3][sm] = av.w;
    *reinterpret_cast<float4*>(&Ws[0][sk][sn4]) = wv;
  }
  __syncthreads();
  float acc[2][2] = {};
  int pb = 0;
  for (int kt = 0; kt < K; kt += 32) {
    const bool more = (kt + 32) < K;
    float4 av2, wv2;
    if (more) {
      av2 = *reinterpret_cast<const float4*>(A + (size_t)(bm + sm) * K + kt + 32 + sk4);
      loadW(kt + 32, wv2);
    }
    #pragma unroll
    for (int k = 0; k < 32; ++k) {
      const float2 a = *reinterpret_cast<const float2*>(&As[pb][k][tm * 2]);
      const float2 w = *reinterpret_cast<const float2*>(&Ws[pb][k][tn * 2]);
      acc[0][0] = fmaf(a.x, w.x, acc[0][0]);
      acc[0][1] = fmaf(a.x, w.y, acc[0][1]);
      acc[1][0] = fmaf(a.y, w.x, acc[1][0]);
      acc[1][1] = fmaf(a.y, w.y, acc[1][1]);
    }
    if (more) {
      const int nb = pb ^ 1;
      As[nb][sk4 + 0][sm] = av2.x; As[nb][sk4 + 1][sm] = av2.y;
      As[nb][sk4 + 2][sm] = av2.z; As[nb][sk4 + 3][sm] = av2.w;
      *reinterpret_cast<float4*>(&Ws[nb][sk][sn4]) = wv2;
      __syncthreads();
      pb = nb;
    }
  }
  #pragma unroll
  for (int j = 0; j < 2; ++j) {
    const int n = bn + tn * 2 + j;
    if (n >= N) continue;
    const float bv = bias[n];
    #pragma unroll
    for (int i = 0; i < 2; ++i) {
      const int m = bm + tm * 2 + i;
      float v = acc[i][j] + bv;
      if (RELU) v = fmaxf(v, 0.f);
      out[(size_t)m * N + n] = v;
    }
  }
}

// ---------------- MU GEMM: -> indiv_prob, CE partials, rmuB/yB [b][c] padded ----------------
__global__ __launch_bounds__(256) void gemm32_mu(
    const float* __restrict__ A, const float* __restrict__ W,
    const float* __restrict__ bias, const float* __restrict__ Y,
    const float* __restrict__ sqrtcov,
    float* __restrict__ out_prob, float* __restrict__ rmuB, float* __restrict__ yB,
    float* __restrict__ ce_part, int M, int N, int K) {
  __shared__ float As[2][32][36];
  __shared__ float Ws[2][32][36];
  const int tid = threadIdx.x;
  const int bn = blockIdx.x * 32, bm = blockIdx.y * 32;
  const int sm = tid >> 3, sk4 = (tid & 7) * 4;
  const int sk = tid >> 3, sn4 = (tid & 7) * 4;
  const int tn = tid & 15, tm = tid >> 4;

  auto loadW = [&](int kt, float4& wv) {
    const float* wrow = W + (size_t)(kt + sk) * N;
    const int nn = bn + sn4;
    if (nn + 3 < N) wv = *reinterpret_cast<const float4*>(wrow + nn);
    else {
      wv.x = (nn + 0 < N) ? wrow[nn + 0] : 0.f;
      wv.y = (nn + 1 < N) ? wrow[nn + 1] : 0.f;
      wv.z = (nn + 2 < N) ? wrow[nn + 2] : 0.f;
      wv.w = (nn + 3 < N) ? wrow[nn + 3] : 0.f;
    }
  };
  {
    float4 av = *reinterpret_cast<const float4*>(A + (size_t)(bm + sm) * K + sk4);
    float4 wv; loadW(0, wv);
    As[0][sk4 + 0][sm] = av.x; As[0][sk4 + 1][sm] = av.y;
    As[0][sk4 + 2][sm] = av.z; As[0][sk4 + 3][sm] = av.w;
    *reinterpret_cast<float4*>(&Ws[0][sk][sn4]) = wv;
  }
  __syncthreads();
  float acc[2][2] = {};
  int pb = 0;
  for (int kt = 0; kt < K; kt += 32) {
    const bool more = (kt + 32) < K;
    float4 av2, wv2;
    if (more) {
      av2 = *reinterpret_cast<const float4*>(A + (size_t)(bm + sm) * K + kt + 32 + sk4);
      loadW(kt + 32, wv2);
    }
    #pragma unroll
    for (int k = 0; k < 32; ++k) {
      const float2 a = *reinterpret_cast<const float2*>(&As[pb][k][tm * 2]);
      const float2 w = *reinterpret_cast<const float2*>(&Ws[pb][k][tn * 2]);
      acc[0][0] = fmaf(a.x, w.x, acc[0][0]);
      acc[0][1] = fmaf(a.x, w.y, acc[0][1]);
      acc[1][0] = fmaf(a.y, w.x, acc[1][0]);
      acc[1][1] = fmaf(a.y, w.y, acc[1][1]);
    }
    if (more) {
      const int nb = pb ^ 1;
      As[nb][sk4 + 0][sm] = av2.x; As[nb][sk4 + 1][sm] = av2.y;
      As[nb][sk4 + 2][sm] = av2.z; As[nb][sk4 + 3][sm] = av2.w;
      *reinterpret_cast<float4*>(&Ws[nb][sk][sn4]) = wv2;
      __syncthreads();
      pb = nb;
    }
  }
  float ce2[2] = {0.f, 0.f};
  #pragma unroll
  for (int i = 0; i < 2; ++i) {
    const int m = bm + tm * 2 + i;
    #pragma unroll
    for (int j = 0; j < 2; ++j) {
      const int n = bn + tn * 2 + j;
      if (n < N) {
        const float v = acc[i][j] + bias[n];
        const float sp = 1.f / (1.f + __expf(-1.70169f * v));
        const float p = fmaf(sp, 1.f - EPS1f, 0.5f * EPS1f);
        const float q = fmaf(1.f - sp, 1.f - EPS1f, 0.5f * EPS1f);
        const float y = Y[(size_t)m * N + n];
        out_prob[(size_t)m * N + n] = p;
        ce2[i] += __logf((y > 0.5f) ? p : q);
        rmuB[(size_t)m * 512 + n] = v * sqrtcov[n];
        yB[(size_t)m * 512 + n] = y;
      }
    }
  }
  #pragma unroll
  for (int off = 1; off < 16; off <<= 1) {
    ce2[0] += __shfl_xor(ce2[0], off, 64);
    ce2[1] += __shfl_xor(ce2[1], off, 64);
  }
  if (tn == 0) {
    const int m0 = bm + tm * 2;
    ce_part[(size_t)blockIdx.x * Bsz + m0] = ce2[0];
    ce_part[(size_t)blockIdx.x * Bsz + m0 + 1] = ce2[1];
  }
}

// ---------------- HOT: s-inner MFMA + probit log-likelihood ----------------
// wave = one (ct, bt) 16c x 16b tile; rmu/y/R resident; loops 25 s.
// mfma(Rf, nf): acc[j] at lane(cl,grp) = x[c0+grp*4+j][b0+cl]
__global__ __launch_bounds__(256) void logprob_s(
    const short* __restrict__ nfB, const short* __restrict__ Rb,
    const float* __restrict__ rmuB, const float* __restrict__ yB,
    float* __restrict__ lp_part) {
  const int blk = blockIdx.x;          // sg*256 + ctg*32 + bt  (1024)
  const int bt = blk & 31;
  const int ctg = (blk >> 5) & 7;
  const int sg = blk >> 8;
  const int wid = threadIdx.x >> 6;
  const int lane = threadIdx.x & 63;
  const int cl = lane & 15, grp = lane >> 4;
  const int ct = ctg * 4 + wid;
  const int c0 = ct * 16, b0 = bt * 16;

  // resident operands (loaded once)
  const bf16x8 Rf0 = *reinterpret_cast<const bf16x8*>(Rb + (size_t)(c0 + cl) * 64 + grp * 8);
  const bf16x8 Rf1 = *reinterpret_cast<const bf16x8*>(Rb + (size_t)(c0 + cl) * 64 + 32 + grp * 8);
  const int cb = c0 + grp * 4;
  const float4 rmu4 = *reinterpret_cast<const float4*>(rmuB + (size_t)(b0 + cl) * 512 + cb);
  const float4 y4   = *reinterpret_cast<const float4*>(yB + (size_t)(b0 + cl) * 512 + cb);
  const float sg0 = fmaf(2.f, y4.x, -1.f), sg1 = fmaf(2.f, y4.y, -1.f);
  const float sg2 = fmaf(2.f, y4.z, -1.f), sg3 = fmaf(2.f, y4.w, -1.f);
  const bool v0 = cb + 0 < Csz, v1 = cb + 1 < Csz, v2 = cb + 2 < Csz, v3 = cb + 3 < Csz;

  const bf16x8* nf = reinterpret_cast<const bf16x8*>(nfB);
  const int sbase = sg * 25;
  int base = (sbase * 32 + bt) * 128 + lane;
  bf16x8 c0f = nf[base], c1f = nf[base + 64];

  for (int i = 0; i < 25; ++i) {
    const int nbase = base + 4096;            // next s
    bf16x8 p0, p1;
    if (i < 24) { p0 = nf[nbase]; p1 = nf[nbase + 64]; }
    f32x4 acc = {0.f, 0.f, 0.f, 0.f};
    acc = __builtin_amdgcn_mfma_f32_16x16x32_bf16(Rf0, c0f, acc, 0, 0, 0);
    acc = __builtin_amdgcn_mfma_f32_16x16x32_bf16(Rf1, c1f, acc, 0, 0, 0);
    float lpl = 0.f;
    lpl += v0 ? log_probit((acc[0] + rmu4.x) * sg0) : 0.f;
    lpl += v1 ? log_probit((acc[1] + rmu4.y) * sg1) : 0.f;
    lpl += v2 ? log_probit((acc[2] + rmu4.z) * sg2) : 0.f;
    lpl += v3 ? log_probit((acc[3] + rmu4.w) * sg3) : 0.f;
    lpl += __shfl_xor(lpl, 16, 64);
    lpl += __shfl_xor(lpl, 32, 64);
    if (lane < 16) {
      const int s = sbase + i;
      lp_part[(size_t)(s * 32 + ct) * 512 + b0 + lane] = lpl;
    }
    c0f = p0; c1f = p1; base = nbase;
  }
}

// ---------------- ct-sum: lp_sum[s][b] = sum_ct lp_part[s][ct][b] ----------------
__global__ __launch_bounds__(256) void ctsum(const float* __restrict__ lp_part,
                                             float* __restrict__ lp_sum) {
  const int i = blockIdx.x * 256 + threadIdx.x;   // 51200
  const int s = i >> 9, b = i & 511;
  const float* p = lp_part + (size_t)s * 16384 + b;
  float a0 = 0.f, a1 = 0.f, a2 = 0.f, a3 = 0.f;
  #pragma unroll
  for (int ct = 0; ct < 32; ct += 4) {
    a0 += p[(ct + 0) * 512];
    a1 += p[(ct + 1) * 512];
    a2 += p[(ct + 2) * 512];
    a3 += p[(ct + 3) * 512];
  }
  lp_sum[i] = (a0 + a1) + (a2 + a3);
}

// ---------------- per-b log-sum-exp over S (4-way s-parallel) ----------------
__global__ __launch_bounds__(256) void nll_kernel(const float* __restrict__ lp_sum,
                                                  float* __restrict__ nll_b) {
  __shared__ float sm[4][64], sse[4][64];
  const int bl = threadIdx.x & 63;
  const int sc = threadIdx.x >> 6;
  const int b = blockIdx.x * 64 + bl;
  float m = -3.0e38f, se = 0.f;
  for (int s = sc * 25; s < sc * 25 + 25; ++s) {
    const float v = lp_sum[(size_t)s * Bsz + b];
    const float mn = fmaxf(m, v);
    se = se * __expf(m - mn) + __expf(v - mn);
    m = mn;
  }
  sm[sc][bl] = m; sse[sc][bl] = se;
  __syncthreads();
  if (sc == 0) {
    float M = sm[0][bl];
    #pragma unroll
    for (int i = 1; i < 4; ++i) M = fmaxf(M, sm[i][bl]);
    float SE = 0.f;
    #pragma unroll
    for (int i = 0; i < 4; ++i) SE += sse[i][bl] * __expf(sm[i][bl] - M);
    nll_b[b] = -__logf(SE * (1.f / (float)Ssz)) - M;
  }
}

// ---------------- L2 partials ----------------
__global__ __launch_bounds__(256) void l2_partial(
    const float* __restrict__ Wa, int na, const float* __restrict__ Wb, int nb,
    const float* __restrict__ Wc, int nc, const float* __restrict__ Wd, int nd,
    float* __restrict__ part) {
  __shared__ float red[4];
  const int gid = blockIdx.x * 256 + threadIdx.x;
  const int stride = gridDim.x * 256;
  float s = 0.f;
  for (int i = gid; i < na; i += stride) { float v = Wa[i]; s = fmaf(v, v, s); }
  for (int i = gid; i < nb; i += stride) { float v = Wb[i]; s = fmaf(v, v, s); }
  for (int i = gid; i < nc; i += stride) { float v = Wc[i]; s = fmaf(v, v, s); }
  for (int i = gid; i < nd; i += stride) { float v = Wd[i]; s = fmaf(v, v, s); }
  const float tot = block_reduce_sum(s, red);
  if (threadIdx.x == 0) part[blockIdx.x] = tot;
}

// ---------------- final scalars ----------------
__global__ __launch_bounds__(256) void finals_kernel(
    const float* __restrict__ nll_b, const float* __restrict__ ce_part,
    const float* __restrict__ l2_part, int nparts, float* __restrict__ out4) {
  __shared__ float red[4];
  const int t = threadIdx.x;
  const float snll = block_reduce_sum(nll_b[t] + nll_b[t + 256], red);
  float ce = 0.f;
  #pragma unroll
  for (int i = 0; i < 32; ++i) ce += ce_part[i * 256 + t];
  const float sce = block_reduce_sum(ce, red);
  const float sl2 = block_reduce_sum((t < nparts) ? l2_part[t] : 0.f, red);
  if (t == 0) {
    const float nll = snll / (float)Bsz;
    const float marg = -sce / (float)Bsz;
    const float l2v = WDf * sl2;
    out4[0] = nll;
    out4[1] = marg;
    out4[2] = l2v;
    out4[3] = l2v + nll;
  }
}

// ---------------- launch ----------------
extern "C" void kernel_launch(void* const* d_in, const int* in_sizes, int n_in,
                              void* d_out, int out_size, void* d_ws, size_t ws_size,
                              hipStream_t stream) {
  const float* X = (const float*)d_in[0];
  const float* Y = (const float*)d_in[1];
  const float* noise = (const float*)d_in[2];
  const float* W1 = (const float*)d_in[3];
  const float* b1 = (const float*)d_in[4];
  const float* W2 = (const float*)d_in[5];
  const float* b2 = (const float*)d_in[6];
  const float* W3 = (const float*)d_in[7];
  const float* b3 = (const float*)d_in[8];
  const float* Wmu = (const float*)d_in[9];
  const float* bmu = (const float*)d_in[10];
  const float* rss = (const float*)d_in[11];

  float* ws = (float*)d_ws;
  // lp_part aliases trunk temporaries (h*, feat dead before logprob writes)
  float* lp_part = ws;                    // 32*100*512 = 1638400
  float* h1 = ws;                         // 512*128
  float* h2 = h1 + 65536;                 // 512*256
  float* feat = h2 + 131072;              // 512*256   (ends 327680 < 1638400)
  float* B0 = ws + 1638400;
  float* sqrtcov = B0;                    // 512
  float* rmuB = sqrtcov + 512;            // 512*512
  float* yB = rmuB + 262144;              // 512*512
  float* ce_part = yB + 262144;           // 16*512
  float* nll_b = ce_part + 8192;          // 512
  float* l2_part = nll_b + 512;           // 128
  float* lp_sum = l2_part + 128;          // 100*512 = 51200
  short* Rb = (short*)(lp_sum + 51200);   // 512*64 shorts (16384 floats)
  short* nfB = (short*)(lp_sum + 51200 + 16384);  // 100*32*128*8 shorts = 1638400 floats

  float* out_prob = (float*)d_out;
  float* out4 = out_prob + (size_t)Bsz * Csz;

  nprep<<<dim3(800), 256, 0, stream>>>(noise, nfB);
  rprep<<<dim3(512), 64, 0, stream>>>(rss, Rb, sqrtcov);

  gemm32<true><<<dim3(4, 16), 256, 0, stream>>>(X, W1, b1, h1, 512, 128, 512);
  gemm32<true><<<dim3(8, 16), 256, 0, stream>>>(h1, W2, b2, h2, 512, 256, 128);
  gemm32<true><<<dim3(8, 16), 256, 0, stream>>>(h2, W3, b3, feat, 512, 256, 256);
  gemm32_mu<<<dim3(16, 16), 256, 0, stream>>>(feat, Wmu, bmu, Y, sqrtcov,
                                              out_prob, rmuB, yB, ce_part, 512, 500, 256);

  logprob_s<<<dim3(1024), 256, 0, stream>>>(nfB, Rb, rmuB, yB, lp_part);
  ctsum<<<dim3(200), 256, 0, stream>>>(lp_part, lp_sum);
  nll_kernel<<<dim3(8), 256, 0, stream>>>(lp_sum, nll_b);

  l2_partial<<<dim3(64), 256, 0, stream>>>(W1, 65536, W2, 32768, W3, 65536, Wmu, 128000, l2_part);
  finals_kernel<<<dim3(1), 256, 0, stream>>>(nll_b, ce_part, l2_part, 64, out4);
}